// Round 7
// baseline (528.151 us; speedup 1.0000x reference)
//
#include <hip/hip_runtime.h>
#include <math.h>

#define TT 512
#define DD 256
#define BIGF 9999.0f
#define KK 8
#define NBLK 128   // 4 rows per block, both kernels
#define REP 16     // instrumentation: dot-phase repeat factor (result identical)

// ws layout (bytes)
#define HT_OFF    0          // float ht[DD][TT]   512 KB  transposed H
#define A_OFF     524288     // float a[TT]
#define B_OFF     526336     // float b[TT]
#define MB_OFF    528384     // ull   mb[TT][4]
#define MSEP_OFF  544768     // float msep4[NBLK]  per-4-row-group masked MSE

typedef unsigned long long ull;

__global__ __launch_bounds__(256) void prep_kernel(
    const float* __restrict__ X, const float* __restrict__ H,
    const float* __restrict__ C, const int* __restrict__ M,
    float* __restrict__ ht, float* __restrict__ A, float* __restrict__ B,
    ull* __restrict__ MB, float* __restrict__ MSEP4, float* __restrict__ out) {
  const int b = blockIdx.x;
  const int t = threadIdx.x;
  const int wid = t >> 6, lane = t & 63;
  const int i0 = 4 * b;
  if (b == 0 && t == 0) out[0] = 0.0f;  // re-arm accumulator every call

  __shared__ float sA[4][4], sB[4][4], sM[4][4];
  float hv[4];
#pragma unroll
  for (int r = 0; r < 4; ++r) {
    const int idx = (i0 + r) * DD + t;
    const float x = X[idx], h = H[idx], c = C[idx];
    const int m = M[idx];
    hv[r] = h;
    const float e = m ? (x - h + c) : 0.0f;
    float pm = e * e, ph = h, ph2 = h * h;
#pragma unroll
    for (int s = 1; s < 64; s <<= 1) {
      pm  += __shfl_xor(pm, s);
      ph  += __shfl_xor(ph, s);
      ph2 += __shfl_xor(ph2, s);
    }
    const ull bal = __ballot(m != 0);
    if (lane == 0) {
      sA[r][wid] = ph; sB[r][wid] = ph2; sM[r][wid] = pm;
      MB[(i0 + r) * 4 + wid] = bal;
    }
  }
  // transpose write: ht[d=t][i0..i0+3], 16B aligned, full sectors
  *(float4*)(ht + t * TT + i0) = make_float4(hv[0], hv[1], hv[2], hv[3]);
  __syncthreads();
  if (t < 4) {
    A[i0 + t] = sA[t][0] + sA[t][1] + sA[t][2] + sA[t][3];
    B[i0 + t] = sB[t][0] + sB[t][1] + sB[t][2] + sB[t][3];
  }
  if (t == 0) {
    float ms = 0.0f;
#pragma unroll
    for (int r = 0; r < 4; ++r)
#pragma unroll
      for (int wq = 0; wq < 4; ++wq) ms += sM[r][wq];
    MSEP4[b] = ms;
  }
}

// 128 blocks x 256 threads; block owns rows i0..i0+3, thread t owns j={2t,2t+1}.
// INSTRUMENTED: dot phase repeated REP times (asm sinks prevent DCE/LICM);
// final rep's values are the real ones, so output is bit-identical to r6.
__global__ __launch_bounds__(256) void score_kernel(
    const float* __restrict__ ht, const float* __restrict__ A,
    const float* __restrict__ B, const ull* __restrict__ MB,
    const float* __restrict__ MSEP4, float* __restrict__ out) {
  __shared__ float dl[4][TT];
  __shared__ float nrm[4][TT];
  const int b = blockIdx.x;
  const int t = threadIdx.x;
  const int wid = t >> 6, lane = t & 63;
  const int i0 = 4 * b;

  float acc[4][2];
  const float* __restrict__ pi = ht + i0;
  const float* __restrict__ pj = ht + 2 * t;
#pragma unroll 1
  for (int rep = 0; rep < REP; ++rep) {
    int zr;
    asm volatile("v_mov_b32 %0, 0" : "=v"(zr));  // opaque 0: defeats LICM
    const float* __restrict__ pir = pi + zr;
    const float* __restrict__ pjr = pj + zr;
    acc[0][0] = 0.f; acc[0][1] = 0.f; acc[1][0] = 0.f; acc[1][1] = 0.f;
    acc[2][0] = 0.f; acc[2][1] = 0.f; acc[3][0] = 0.f; acc[3][1] = 0.f;
#pragma unroll 8
    for (int d = 0; d < DD; ++d) {
      const float4 hi = *(const float4*)(pir + d * TT);   // uniform, 1 line/wave
      const float2 hj = *(const float2*)(pjr + d * TT);   // coalesced 512B/wave
      acc[0][0] += hi.x * hj.x; acc[0][1] += hi.x * hj.y;
      acc[1][0] += hi.y * hj.x; acc[1][1] += hi.y * hj.y;
      acc[2][0] += hi.z * hj.x; acc[2][1] += hi.z * hj.y;
      acc[3][0] += hi.w * hj.x; acc[3][1] += hi.w * hj.y;
    }
    asm volatile("" :: "v"(acc[0][0]), "v"(acc[0][1]), "v"(acc[1][0]),
                       "v"(acc[1][1]), "v"(acc[2][0]), "v"(acc[2][1]),
                       "v"(acc[3][0]), "v"(acc[3][1]));  // keep each rep live
  }

  float ai[4], bi[4];
  ull mi[4][4];
#pragma unroll
  for (int r = 0; r < 4; ++r) {
    ai[r] = A[i0 + r];
    bi[r] = B[i0 + r];
#pragma unroll
    for (int c = 0; c < 4; ++c) mi[r][c] = MB[(i0 + r) * 4 + c];
  }

#pragma unroll
  for (int jj = 0; jj < 2; ++jj) {
    const int j = 2 * t + jj;
    const float aj = A[j], bj = B[j];
    const ull m0 = MB[j * 4 + 0], m1 = MB[j * 4 + 1],
              m2 = MB[j * 4 + 2], m3 = MB[j * 4 + 3];
#pragma unroll
    for (int r = 0; r < 4; ++r) {
      const float dot = acc[r][jj];
      const float s2 = bi[r] + bj - 2.0f * dot;
      const float s1 = ai[r] - aj;
      const float var = (s2 - s1 * s1 * (1.0f / DD)) * (1.0f / (DD - 1));
      const bool diff = (m0 != mi[r][0]) | (m1 != mi[r][1]) |
                        (m2 != mi[r][2]) | (m3 != mi[r][3]);
      const bool valid = diff && (j != i0 + r);
      dl[r][j] = valid ? sqrtf(fmaxf(var, 0.0f)) : BIGF;
      nrm[r][j] = sqrtf(fmaxf(s2, 0.0f));
    }
  }
  __syncthreads();

  // wave w -> row i0+w: iterative top-8 smallest, lowest-index tie-break
  __shared__ float s_rl[4];
  {
    const int w = wid;
    float cv[8];
#pragma unroll
    for (int c = 0; c < 8; ++c) cv[c] = dl[w][lane + 64 * c];

    float kv[KK];
    int ki[KK];
#pragma unroll
    for (int k = 0; k < KK; ++k) {
      float bv = cv[0];
      int bc = 0;
#pragma unroll
      for (int c = 1; c < 8; ++c) {
        if (cv[c] < bv) { bv = cv[c]; bc = c; }
      }
      int bidx = lane + 64 * bc;
#pragma unroll
      for (int s = 1; s < 64; s <<= 1) {
        const float ov = __shfl_xor(bv, s);
        const int oi = __shfl_xor(bidx, s);
        if (ov < bv || (ov == bv && oi < bidx)) { bv = ov; bidx = oi; }
      }
      kv[k] = bv;
      ki[k] = bidx;
      const int csel = bidx >> 6;
      const bool mine = (bidx & 63) == lane;
#pragma unroll
      for (int c = 0; c < 8; ++c) {
        if (mine && c == csel) cv[c] = BIGF;
      }
    }
    float wsum = 0.0f, rl = 0.0f;
#pragma unroll
    for (int k = 0; k < KK; ++k) {
      const float e = expf(kv[0] - kv[k]);  // kv[0] = min score
      wsum += e;
      rl += e * nrm[w][ki[k]];
    }
    if (lane == 0) s_rl[w] = rl / wsum;
  }
  __syncthreads();

  if (t == 0)
    atomicAdd(out, s_rl[0] + s_rl[1] + s_rl[2] + s_rl[3] + MSEP4[b]);
}

extern "C" void kernel_launch(void* const* d_in, const int* in_sizes, int n_in,
                              void* d_out, int out_size, void* d_ws, size_t ws_size,
                              hipStream_t stream) {
  const float* X = (const float*)d_in[0];
  const float* H = (const float*)d_in[1];
  const float* C = (const float*)d_in[2];
  const int* M = (const int*)d_in[3];
  float* out = (float*)d_out;

  char* ws = (char*)d_ws;
  float* ht = (float*)(ws + HT_OFF);
  float* A = (float*)(ws + A_OFF);
  float* B = (float*)(ws + B_OFF);
  ull* MB = (ull*)(ws + MB_OFF);
  float* MSEP4 = (float*)(ws + MSEP_OFF);

  prep_kernel<<<NBLK, 256, 0, stream>>>(X, H, C, M, ht, A, B, MB, MSEP4, out);
  score_kernel<<<NBLK, 256, 0, stream>>>(ht, A, B, MB, MSEP4, out);
}

// Round 8
// 45.033 us; speedup vs baseline: 11.7281x; 11.7281x over previous
//
#include <hip/hip_runtime.h>
#include <math.h>

#define TT 512
#define DD 256
#define BIGF 9999.0f
#define KK 8
#define NBLK 128   // 4 i-rows per block, 512 threads (8 waves), 1 j per thread

typedef unsigned long long ull;

// Fully self-sufficient block: no inter-block dependencies, no ws usage.
// Block b owns rows i0..i0+3; thread t owns column j=t.
__global__ __launch_bounds__(512, 2) void fused_kernel(
    const float* __restrict__ X, const float* __restrict__ H,
    const float* __restrict__ C, const int* __restrict__ M,
    float* __restrict__ out) {
  __shared__ ull mb[TT][4];       // 16 KB packed masks (permuted-consistent order)
  __shared__ float dl[4][TT];     // 8 KB scores
  __shared__ float nrm[4][TT];    // 8 KB norms
  __shared__ float partA[4][2], partB[4][2], partE[8];
  __shared__ float s_rl[4];

  const int b = blockIdx.x;
  const int t = threadIdx.x;
  const int wv = t >> 6, lane = t & 63;
  const int i0 = 4 * b;

  // ---- Phase A: own-row stats + masked MSE (row r = t>>7, 128 thr/row) ----
  {
    const int r = t >> 7;
    const int dh = (t & 127) << 1;
    const int base = (i0 + r) * DD + dh;
    const float2 x2 = *(const float2*)(X + base);
    const float2 h2 = *(const float2*)(H + base);
    const float2 c2 = *(const float2*)(C + base);
    const int2 m2 = *(const int2*)(M + base);
    float pa = h2.x + h2.y;
    float pb = h2.x * h2.x + h2.y * h2.y;
    const float e0 = x2.x - h2.x + c2.x;
    const float e1 = x2.y - h2.y + c2.y;
    float pe = (m2.x ? e0 * e0 : 0.0f) + (m2.y ? e1 * e1 : 0.0f);
#pragma unroll
    for (int s = 1; s < 64; s <<= 1) {
      pa += __shfl_xor(pa, s);
      pb += __shfl_xor(pb, s);
      pe += __shfl_xor(pe, s);
    }
    if (lane == 0) {
      partA[r][wv & 1] = pa;
      partB[r][wv & 1] = pb;
      partE[wv] = pe;
    }
  }

  // ---- Phase B: pack ALL mask rows (wave wv packs rows 64wv..64wv+63) ----
  {
    const int4* __restrict__ Mv = (const int4*)M;
    const int rbase = wv << 6;
#pragma unroll 4
    for (int q = 0; q < 64; ++q) {
      const int row = rbase + q;
      const int4 v = Mv[row * (DD / 4) + lane];
      const ull b0 = __ballot(v.x != 0);
      const ull b1 = __ballot(v.y != 0);
      const ull b2 = __ballot(v.z != 0);
      const ull b3 = __ballot(v.w != 0);
      if (lane < 4) {
        ull bs = b0;
        if (lane == 1) bs = b1;
        if (lane == 2) bs = b2;
        if (lane == 3) bs = b3;
        mb[row][lane] = bs;
      }
    }
  }
  __syncthreads();

  // ---- Phase C: dots + on-the-fly a_j, b_j (thread t walks row H[j=t]) ----
  float acc0 = 0.f, acc1 = 0.f, acc2 = 0.f, acc3 = 0.f, aj = 0.f, bj = 0.f;
  {
    const float* __restrict__ hjp = H + t * DD;         // per-thread row walk
    const float* __restrict__ hip = H + i0 * DD;        // wave-uniform -> s_load
#pragma unroll 8
    for (int c = 0; c < 64; ++c) {
      const float4 hj = *(const float4*)(hjp + 4 * c);
      const float4 h0 = *(const float4*)(hip + 0 * DD + 4 * c);
      const float4 h1 = *(const float4*)(hip + 1 * DD + 4 * c);
      const float4 h2 = *(const float4*)(hip + 2 * DD + 4 * c);
      const float4 h3 = *(const float4*)(hip + 3 * DD + 4 * c);
      aj += (hj.x + hj.y) + (hj.z + hj.w);
      bj += hj.x * hj.x + hj.y * hj.y + hj.z * hj.z + hj.w * hj.w;
      acc0 += h0.x * hj.x + h0.y * hj.y + h0.z * hj.z + h0.w * hj.w;
      acc1 += h1.x * hj.x + h1.y * hj.y + h1.z * hj.z + h1.w * hj.w;
      acc2 += h2.x * hj.x + h2.y * hj.y + h2.z * hj.z + h2.w * hj.w;
      acc3 += h3.x * hj.x + h3.y * hj.y + h3.z * hj.z + h3.w * hj.w;
    }
  }

  // ---- Phase D: scores + norms for (i0..i0+3, j=t) ----
  {
    const ull mj0 = mb[t][0], mj1 = mb[t][1], mj2 = mb[t][2], mj3 = mb[t][3];
    const float accs[4] = {acc0, acc1, acc2, acc3};
#pragma unroll
    for (int r = 0; r < 4; ++r) {
      const float ai = partA[r][0] + partA[r][1];
      const float bi = partB[r][0] + partB[r][1];
      const float s2 = bi + bj - 2.0f * accs[r];
      const float s1 = ai - aj;
      const float var = (s2 - s1 * s1 * (1.0f / DD)) * (1.0f / (DD - 1));
      const bool diff = (mj0 != mb[i0 + r][0]) | (mj1 != mb[i0 + r][1]) |
                        (mj2 != mb[i0 + r][2]) | (mj3 != mb[i0 + r][3]);
      const bool valid = diff && (t != i0 + r);
      dl[r][t] = valid ? sqrtf(fmaxf(var, 0.0f)) : BIGF;
      nrm[r][t] = sqrtf(fmaxf(s2, 0.0f));
    }
  }
  __syncthreads();

  // ---- Phase E: waves 0-3, per-row iterative top-8 (lowest-index ties) ----
  if (wv < 4) {
    const int w = wv;
    float cv[8];
#pragma unroll
    for (int c = 0; c < 8; ++c) cv[c] = dl[w][lane + 64 * c];

    float kv[KK];
    int ki[KK];
#pragma unroll
    for (int k = 0; k < KK; ++k) {
      float bv = cv[0];
      int bc = 0;
#pragma unroll
      for (int c = 1; c < 8; ++c) {
        if (cv[c] < bv) { bv = cv[c]; bc = c; }
      }
      int bidx = lane + 64 * bc;
#pragma unroll
      for (int s = 1; s < 64; s <<= 1) {
        const float ov = __shfl_xor(bv, s);
        const int oi = __shfl_xor(bidx, s);
        if (ov < bv || (ov == bv && oi < bidx)) { bv = ov; bidx = oi; }
      }
      kv[k] = bv;
      ki[k] = bidx;
      const int csel = bidx >> 6;
      const bool mine = (bidx & 63) == lane;
#pragma unroll
      for (int c = 0; c < 8; ++c) {
        if (mine && c == csel) cv[c] = BIGF;
      }
    }
    float wsum = 0.0f, rl = 0.0f;
#pragma unroll
    for (int k = 0; k < KK; ++k) {
      const float e = expf(kv[0] - kv[k]);  // kv[0] = min score
      wsum += e;
      rl += e * nrm[w][ki[k]];
    }
    if (lane == 0) s_rl[w] = rl / wsum;
  }
  __syncthreads();

  // ---- Tail: one atomicAdd per block (device-coherent, fence-free) ----
  if (t == 0) {
    float mse = 0.0f;
#pragma unroll
    for (int q = 0; q < 8; ++q) mse += partE[q];
    atomicAdd(out, s_rl[0] + s_rl[1] + s_rl[2] + s_rl[3] + mse);
  }
}

extern "C" void kernel_launch(void* const* d_in, const int* in_sizes, int n_in,
                              void* d_out, int out_size, void* d_ws, size_t ws_size,
                              hipStream_t stream) {
  const float* X = (const float*)d_in[0];
  const float* H = (const float*)d_in[1];
  const float* C = (const float*)d_in[2];
  const int* M = (const int*)d_in[3];
  float* out = (float*)d_out;

  hipMemsetAsync(out, 0, sizeof(float), stream);
  fused_kernel<<<NBLK, 512, 0, stream>>>(X, H, C, M, out);
}